// Round 1
// baseline (366.335 us; speedup 1.0000x reference)
//
#include <hip/hip_runtime.h>
#include <math.h>

#define NV 778
#define KROW 2334   // NV*3

// ---------------- Kernel 1: SJ[k][j][c] = sum_v shapedirs[k][3v+c]*Jreg[v][j], J0[j][c] from v_template
__global__ void k1_sj(const float* __restrict__ shapedirs,
                      const float* __restrict__ v_template,
                      const float* __restrict__ Jreg,
                      float* __restrict__ SJ, float* __restrict__ J0)
{
    const int j = blockIdx.x / 3;
    const int c = blockIdx.x % 3;
    const int t = threadIdx.x;
    float acc[11];
#pragma unroll
    for (int k = 0; k < 11; ++k) acc[k] = 0.f;
    for (int v = t; v < NV; v += 64) {
        const float jr = Jreg[v*21 + j];
        acc[10] += v_template[v*3 + c] * jr;
#pragma unroll
        for (int k = 0; k < 10; ++k)
            acc[k] += shapedirs[k*KROW + v*3 + c] * jr;
    }
#pragma unroll
    for (int k = 0; k < 11; ++k) {
        float s = acc[k];
#pragma unroll
        for (int off = 32; off >= 1; off >>= 1) s += __shfl_down(s, off, 64);
        acc[k] = s;
    }
    if (t == 0) {
#pragma unroll
        for (int k = 0; k < 10; ++k) SJ[k*48 + j*3 + c] = acc[k];
        J0[j*3 + c] = acc[10];
    }
}

// ---------------- Kernel 2a: per (batch, joint) Rodrigues; writes R_g[b][16][9], coef[b][145]
__global__ void k2a_rot(const float* __restrict__ theta,
                        const float* __restrict__ wrist,
                        const float* __restrict__ hc,     // [10][45]
                        const float* __restrict__ hm,     // [45]
                        const float* __restrict__ beta,
                        float* __restrict__ R_g,
                        float* __restrict__ coef_g, int B)
{
    const int g = blockIdx.x * 256 + threadIdx.x;
    if (g >= B * 16) return;
    const int b = g >> 4, i = g & 15;
    float r0, r1, r2;
    if (i == 0) {
        r0 = wrist[b*3+0]; r1 = wrist[b*3+1]; r2 = wrist[b*3+2];
#pragma unroll
        for (int k = 0; k < 10; ++k) coef_g[(size_t)b*145 + k] = beta[b*10 + k];
    } else {
        const int col = (i-1)*3;
        float e0 = hm[col], e1 = hm[col+1], e2 = hm[col+2];
#pragma unroll
        for (int k = 0; k < 10; ++k) {
            const float th = theta[b*10 + k];
            e0 += th * hc[k*45 + col];
            e1 += th * hc[k*45 + col+1];
            e2 += th * hc[k*45 + col+2];
        }
        r0 = e0; r1 = e1; r2 = e2;
    }
    // rodrigues: angle = ||r + 1e-8||, axis = r/angle  (matches reference exactly)
    const float x_ = r0 + 1e-8f, y_ = r1 + 1e-8f, z_ = r2 + 1e-8f;
    const float angle = sqrtf(x_*x_ + y_*y_ + z_*z_);
    const float inv = 1.0f / angle;
    const float x = r0*inv, y = r1*inv, z = r2*inv;
    const float s = sinf(angle), c = cosf(angle);
    const float t1 = 1.0f - c;
    float R[9];
    R[0] = 1.f - t1*(y*y + z*z);
    R[1] = -s*z + t1*x*y;
    R[2] =  s*y + t1*x*z;
    R[3] =  s*z + t1*x*y;
    R[4] = 1.f - t1*(x*x + z*z);
    R[5] = -s*x + t1*y*z;
    R[6] = -s*y + t1*x*z;
    R[7] =  s*x + t1*y*z;
    R[8] = 1.f - t1*(x*x + y*y);
    float* Rd = R_g + (size_t)b*144 + i*9;
#pragma unroll
    for (int q = 0; q < 9; ++q) Rd[q] = R[q];
    if (i > 0) {
        float* pf = coef_g + (size_t)b*145 + 10 + (i-1)*9;
#pragma unroll
        for (int q = 0; q < 9; ++q)
            pf[q] = R[q] - ((q == 0 || q == 4 || q == 8) ? 1.f : 0.f);
    }
}

// ---------------- Kernel 2b: kinematic chain -> A[b][16][12] (rows [R|t-R*J])
__global__ void k2b_chain(const float* __restrict__ beta,
                          const float* __restrict__ R_g,
                          const float* __restrict__ SJ,
                          const float* __restrict__ J0,
                          float* __restrict__ A_g, int B)
{
    const int b = blockIdx.x * 64 + threadIdx.x;
    if (b >= B) return;
    float bt[10];
#pragma unroll
    for (int k = 0; k < 10; ++k) bt[k] = beta[b*10 + k];

    const float* Rb = R_g + (size_t)b*144;
    float* Ab = A_g + (size_t)b*192;

    // J for joint j
    auto jointJ = [&](int j, float* o) {
        float j0 = J0[j*3+0], j1 = J0[j*3+1], j2 = J0[j*3+2];
#pragma unroll
        for (int k = 0; k < 10; ++k) {
            j0 += bt[k] * SJ[k*48 + j*3 + 0];
            j1 += bt[k] * SJ[k*48 + j*3 + 1];
            j2 += bt[k] * SJ[k*48 + j*3 + 2];
        }
        o[0] = j0; o[1] = j1; o[2] = j2;
    };

    float G0R[9], J0v[3];
#pragma unroll
    for (int q = 0; q < 9; ++q) G0R[q] = Rb[q];
    jointJ(0, J0v);
#pragma unroll
    for (int r = 0; r < 3; ++r) {
        const float at = J0v[r] - (G0R[r*3+0]*J0v[0] + G0R[r*3+1]*J0v[1] + G0R[r*3+2]*J0v[2]);
        Ab[r*4+0] = G0R[r*3+0]; Ab[r*4+1] = G0R[r*3+1]; Ab[r*4+2] = G0R[r*3+2]; Ab[r*4+3] = at;
    }
    // 5 chains of 3 joints each from root: joints {1,2,3},{4,5,6},...
    for (int ch = 0; ch < 5; ++ch) {
        float GpR[9], Gpt[3], Jp[3];
#pragma unroll
        for (int q = 0; q < 9; ++q) GpR[q] = G0R[q];
        Gpt[0] = J0v[0]; Gpt[1] = J0v[1]; Gpt[2] = J0v[2];
        Jp[0] = J0v[0]; Jp[1] = J0v[1]; Jp[2] = J0v[2];
        for (int s = 0; s < 3; ++s) {
            const int j = ch*3 + 1 + s;
            float Rl[9];
            const float* Rj = Rb + j*9;
#pragma unroll
            for (int q = 0; q < 9; ++q) Rl[q] = Rj[q];
            float Jc[3];
            jointJ(j, Jc);
            const float tl0 = Jc[0]-Jp[0], tl1 = Jc[1]-Jp[1], tl2 = Jc[2]-Jp[2];
            float GR[9], Gt[3];
#pragma unroll
            for (int r = 0; r < 3; ++r) {
#pragma unroll
                for (int cc = 0; cc < 3; ++cc)
                    GR[r*3+cc] = GpR[r*3+0]*Rl[0*3+cc] + GpR[r*3+1]*Rl[1*3+cc] + GpR[r*3+2]*Rl[2*3+cc];
                Gt[r] = GpR[r*3+0]*tl0 + GpR[r*3+1]*tl1 + GpR[r*3+2]*tl2 + Gpt[r];
            }
            float* Aj = Ab + j*12;
#pragma unroll
            for (int r = 0; r < 3; ++r) {
                const float at = Gt[r] - (GR[r*3+0]*Jc[0] + GR[r*3+1]*Jc[1] + GR[r*3+2]*Jc[2]);
                Aj[r*4+0] = GR[r*3+0]; Aj[r*4+1] = GR[r*3+1]; Aj[r*4+2] = GR[r*3+2]; Aj[r*4+3] = at;
            }
#pragma unroll
            for (int q = 0; q < 9; ++q) GpR[q] = GR[q];
            Gpt[0] = Gt[0]; Gpt[1] = Gt[1]; Gpt[2] = Gt[2];
            Jp[0] = Jc[0]; Jp[1] = Jc[1]; Jp[2] = Jc[2];
        }
    }
}

// ---------------- Kernel 3: fused blend-shapes + LBS + joint regression
// block = 256 threads handles BM=16 batches; vertices processed in 4 chunks of 256.
#define BM 16
__global__ __launch_bounds__(256, 2)
void k3_fused(const float* __restrict__ coef_g,   // [B][145]  (beta | pose_feature)
              const float* __restrict__ A_g,      // [B][16*12]
              const float* __restrict__ shapedirs,
              const float* __restrict__ posedirs,
              const float* __restrict__ v_template,
              const float* __restrict__ weights,  // [778][16]
              const float* __restrict__ Jreg,     // [778][21]
              float* __restrict__ out, int B)
{
    __shared__ __align__(16) float coef_s[145*BM];      // [k][m]
    __shared__ __align__(16) float A_s[BM*196];         // [m][jj*12+e], padded stride 196
    __shared__ __align__(16) float chunk_s[BM*3*256];   // [m][c][vloc]
    __shared__ __align__(16) float jout_s[BM*63];

    const int t  = threadIdx.x;
    const int b0 = blockIdx.x * BM;

    // stage coef (transposed) and A
    {
        const int cmax = B*145 - 1;
        for (int idx = t; idx < 145*BM; idx += 256) {
            const int m = idx / 145, k = idx - m*145;
            coef_s[k*BM + m] = coef_g[min((size_t)b0*145 + idx, (size_t)cmax)];
        }
        const int amax = B*192 - 1;
        for (int idx = t; idx < BM*192; idx += 256) {
            const int m = idx / 192, e = idx - m*192;
            A_s[m*196 + e] = A_g[min((size_t)b0*192 + idx, (size_t)amax)];
        }
    }

    float jacc[63];
#pragma unroll
    for (int i = 0; i < 63; ++i) jacc[i] = 0.f;

    const int mt = t >> 4;   // batch index for phases B/C
    const int lt = t & 15;   // lane within 16-thread group

    __syncthreads();

    for (int chunk = 0; chunk < 4; ++chunk) {
        const int vbase = chunk * 256;
        const int nv = min(256, NV - vbase);   // 256,256,256,10
        const int v = vbase + t;

        // ---- phase A: K=145 blend-shape GEMM, this thread's vertex x 16 batches
        if (t < nv) {
            float a0[BM], a1[BM], a2[BM];
            const float vt0 = v_template[v*3+0];
            const float vt1 = v_template[v*3+1];
            const float vt2 = v_template[v*3+2];
#pragma unroll
            for (int m = 0; m < BM; ++m) { a0[m] = vt0; a1[m] = vt1; a2[m] = vt2; }
            const float4* cs4 = (const float4*)coef_s;
            const float* sp = shapedirs + v*3;
#pragma unroll
            for (int k = 0; k < 10; ++k) {
                const float s0 = sp[0], s1 = sp[1], s2 = sp[2];
                sp += KROW;
#pragma unroll
                for (int q = 0; q < 4; ++q) {
                    const float4 cc = cs4[k*4 + q];
                    a0[4*q+0] += cc.x*s0; a1[4*q+0] += cc.x*s1; a2[4*q+0] += cc.x*s2;
                    a0[4*q+1] += cc.y*s0; a1[4*q+1] += cc.y*s1; a2[4*q+1] += cc.y*s2;
                    a0[4*q+2] += cc.z*s0; a1[4*q+2] += cc.z*s1; a2[4*q+2] += cc.z*s2;
                    a0[4*q+3] += cc.w*s0; a1[4*q+3] += cc.w*s1; a2[4*q+3] += cc.w*s2;
                }
            }
            const float* pp = posedirs + v*3;
#pragma unroll 3
            for (int k = 0; k < 135; ++k) {
                const float s0 = pp[0], s1 = pp[1], s2 = pp[2];
                pp += KROW;
#pragma unroll
                for (int q = 0; q < 4; ++q) {
                    const float4 cc = cs4[(10+k)*4 + q];
                    a0[4*q+0] += cc.x*s0; a1[4*q+0] += cc.x*s1; a2[4*q+0] += cc.x*s2;
                    a0[4*q+1] += cc.y*s0; a1[4*q+1] += cc.y*s1; a2[4*q+1] += cc.y*s2;
                    a0[4*q+2] += cc.z*s0; a1[4*q+2] += cc.z*s1; a2[4*q+2] += cc.z*s2;
                    a0[4*q+3] += cc.w*s0; a1[4*q+3] += cc.w*s1; a2[4*q+3] += cc.w*s2;
                }
            }
#pragma unroll
            for (int m = 0; m < BM; ++m) {
                chunk_s[(m*3+0)*256 + t] = a0[m];
                chunk_s[(m*3+1)*256 + t] = a1[m];
                chunk_s[(m*3+2)*256 + t] = a2[m];
            }
        }
        __syncthreads();

        // ---- phase B: T = sum_jj w*A, verts = T*vph (in-place in chunk_s)
        for (int rnd = 0; rnd < 4; ++rnd) {
            if (rnd*64 >= nv) break;   // uniform skip for tail chunk
            float T[4][12];
#pragma unroll
            for (int vv = 0; vv < 4; ++vv)
#pragma unroll
                for (int e = 0; e < 12; ++e) T[vv][e] = 0.f;
#pragma unroll
            for (int jq = 0; jq < 4; ++jq) {
                float4 ab[12];
                const float4* Am = (const float4*)(A_s + mt*196 + jq*48);
#pragma unroll
                for (int i = 0; i < 12; ++i) ab[i] = Am[i];
#pragma unroll
                for (int vv = 0; vv < 4; ++vv) {
                    const int vloc = lt + 16*(rnd*4 + vv);
                    const int vg = min(vbase + vloc, NV - 1);
                    const float4 wv = *(const float4*)(weights + vg*16 + jq*4);
#pragma unroll
                    for (int e = 0; e < 4; ++e) {
                        const float we = (e == 0) ? wv.x : (e == 1) ? wv.y : (e == 2) ? wv.z : wv.w;
#pragma unroll
                        for (int r = 0; r < 3; ++r) {
                            const float4 a = ab[e*3 + r];
                            T[vv][r*4+0] += we*a.x; T[vv][r*4+1] += we*a.y;
                            T[vv][r*4+2] += we*a.z; T[vv][r*4+3] += we*a.w;
                        }
                    }
                }
            }
#pragma unroll
            for (int vv = 0; vv < 4; ++vv) {
                const int vloc = lt + 16*(rnd*4 + vv);
                if (vloc < nv) {
                    const float hx = chunk_s[(mt*3+0)*256 + vloc];
                    const float hy = chunk_s[(mt*3+1)*256 + vloc];
                    const float hz = chunk_s[(mt*3+2)*256 + vloc];
                    const float vx = T[vv][0]*hx + T[vv][1]*hy + T[vv][2]*hz  + T[vv][3];
                    const float vy = T[vv][4]*hx + T[vv][5]*hy + T[vv][6]*hz  + T[vv][7];
                    const float vz = T[vv][8]*hx + T[vv][9]*hy + T[vv][10]*hz + T[vv][11];
                    chunk_s[(mt*3+0)*256 + vloc] = vx;
                    chunk_s[(mt*3+1)*256 + vloc] = vy;
                    chunk_s[(mt*3+2)*256 + vloc] = vz;
                }
            }
        }
        __syncthreads();

        // ---- phase C: joint regression accumulation (63 register accumulators)
        for (int i = lt; i < nv; i += 16) {
            const float vx = chunk_s[(mt*3+0)*256 + i];
            const float vy = chunk_s[(mt*3+1)*256 + i];
            const float vz = chunk_s[(mt*3+2)*256 + i];
            const float* jr = Jreg + (vbase + i)*21;
#pragma unroll
            for (int j = 0; j < 21; ++j) {
                const float jv = jr[j];
                jacc[3*j+0] += jv*vx;
                jacc[3*j+1] += jv*vy;
                jacc[3*j+2] += jv*vz;
            }
        }
        __syncthreads();
    }

    // reduce across the 16 lanes of each batch-group
#pragma unroll
    for (int i = 0; i < 63; ++i) {
        float s = jacc[i];
        s += __shfl_xor(s, 8, 16);
        s += __shfl_xor(s, 4, 16);
        s += __shfl_xor(s, 2, 16);
        s += __shfl_xor(s, 1, 16);
        jacc[i] = s;
    }
    if (lt == 0) {
#pragma unroll
        for (int i = 0; i < 63; ++i) jout_s[mt*63 + i] = jacc[i];
    }
    __syncthreads();
    const size_t obase = (size_t)b0 * 63;
    const size_t omax = (size_t)B * 63;
    for (int idx = t; idx < BM*63; idx += 256) {
        if (obase + idx < omax) out[obase + idx] = jout_s[idx];
    }
}

extern "C" void kernel_launch(void* const* d_in, const int* in_sizes, int n_in,
                              void* d_out, int out_size, void* d_ws, size_t ws_size,
                              hipStream_t stream) {
    (void)n_in; (void)out_size; (void)ws_size;
    const float* beta       = (const float*)d_in[0];
    const float* theta      = (const float*)d_in[1];
    const float* wrist      = (const float*)d_in[2];
    const float* v_template = (const float*)d_in[3];
    const float* shapedirs  = (const float*)d_in[4];
    const float* posedirs   = (const float*)d_in[5];
    const float* Jreg       = (const float*)d_in[6];
    const float* hc         = (const float*)d_in[7];
    const float* hm         = (const float*)d_in[8];
    const float* weights    = (const float*)d_in[9];
    float* out = (float*)d_out;
    const int B = in_sizes[0] / 10;

    float* ws   = (float*)d_ws;
    float* SJ   = ws;                       // 480
    float* J0   = ws + 480;                 // 48
    float* R_g  = ws + 528;                 // B*144
    float* coef = R_g + (size_t)B*144;      // B*145
    float* A_g  = coef + (size_t)B*145;     // B*192

    k1_sj<<<48, 64, 0, stream>>>(shapedirs, v_template, Jreg, SJ, J0);
    k2a_rot<<<(B*16 + 255)/256, 256, 0, stream>>>(theta, wrist, hc, hm, beta, R_g, coef, B);
    k2b_chain<<<(B + 63)/64, 64, 0, stream>>>(beta, R_g, SJ, J0, A_g, B);
    k3_fused<<<(B + BM - 1)/BM, 256, 0, stream>>>(coef, A_g, shapedirs, posedirs,
                                                  v_template, weights, Jreg, out, B);
}